// Round 5
// baseline (1486.034 us; speedup 1.0000x reference)
//
#include <hip/hip_runtime.h>
#include <hip/hip_fp16.h>
#include <cstdint>
#include <cstddef>

#define NN 100000
#define NE 800000
#define DIM 64
#define HEADS 4
#define HEAD_DIM 16
#define ALPHA 0.1f
#define K_ITERS 8
#define NBLK 391  // ceil(NN/256)

typedef short bf16x8 __attribute__((ext_vector_type(8)));
typedef float f32x4 __attribute__((ext_vector_type(4)));
typedef float fvec4 __attribute__((ext_vector_type(4)));        // nontemporal-capable
typedef unsigned int uvec4 __attribute__((ext_vector_type(4))); // nontemporal-capable

__device__ __forceinline__ unsigned short f2bf(float f) {
    unsigned int x = __float_as_uint(f);
    unsigned int r = (x + 0x7fffu + ((x >> 16) & 1u)) >> 16;  // RNE
    return (unsigned short)r;
}
__device__ __forceinline__ float2 h2f(unsigned int v) {
    __half2 h = *(__half2*)&v;
    return __half22float2(h);
}
__device__ __forceinline__ unsigned int f2h2(float a, float b) {
    __half2 h = __floats2half2_rn(a, b);
    return *(unsigned int*)&h;
}
// sum_i q_i * (k_i + e_i) over 8 fp16 lanes packed in uvec4
__device__ __forceinline__ float dot8s(uvec4 q, uvec4 k, uvec4 e) {
    float2 qa = h2f(q.x), ka = h2f(k.x), ea = h2f(e.x);
    float2 qb = h2f(q.y), kb = h2f(k.y), eb = h2f(e.y);
    float2 qc = h2f(q.z), kc = h2f(k.z), ec = h2f(e.z);
    float2 qd = h2f(q.w), kd = h2f(k.w), ed = h2f(e.w);
    return qa.x * (ka.x + ea.x) + qa.y * (ka.y + ea.y)
         + qb.x * (kb.x + eb.x) + qb.y * (kb.y + eb.y)
         + qc.x * (kc.x + ec.x) + qc.y * (kc.y + ec.y)
         + qd.x * (kd.x + ed.x) + qd.y * (kd.y + ed.y);
}

// NOTE: macro parameter must NOT be named 'z' (or x/y/w) — member tokens
// .x/.y/.z/.w would be substituted too.
#define ACC8(a, V) { float2 t_; \
    t_ = h2f((V).x); m[0] += (a) * t_.x; m[1] += (a) * t_.y; \
    t_ = h2f((V).y); m[2] += (a) * t_.x; m[3] += (a) * t_.y; \
    t_ = h2f((V).z); m[4] += (a) * t_.x; m[5] += (a) * t_.y; \
    t_ = h2f((V).w); m[6] += (a) * t_.x; m[7] += (a) * t_.y; }

// att extractor from packed rec: rec.y holds heads 0,1; rec.z holds heads 2,3.
__device__ __forceinline__ float rec_att(uint4 r, int head) {
    unsigned int pair = (head & 2) ? r.z : r.y;
    float2 f = h2f(pair);
    return (head & 1) ? f.y : f.x;
}

// MFMA qkv: block = 64 nodes, 4 waves x 16 rows each. (u-pass removed: e_proj
// GEMM replaces it.)
__global__ __launch_bounds__(256) void qkv_mfma_kernel(
    const float* __restrict__ x,
    const float* __restrict__ Wq, const float* __restrict__ Wk,
    const float* __restrict__ Wv,
    __half* __restrict__ qh, __half* __restrict__ kh, __half* __restrict__ vh)
{
    int tid = threadIdx.x;
    int w = tid >> 6;
    int lane = tid & 63;
    int m16 = lane & 15;
    int quad = lane >> 4;
    int node = blockIdx.x * 64 + w * 16 + m16;
    int nodeC = node < NN ? node : NN - 1;

    bf16x8 afrag[2];
    #pragma unroll
    for (int kk = 0; kk < 2; ++kk) {
        const float* xr = x + (size_t)nodeC * DIM + kk * 32 + quad * 8;
        #pragma unroll
        for (int j = 0; j < 8; ++j) afrag[kk][j] = (short)f2bf(xr[j]);
    }

    const float* Ws[3] = {Wq, Wk, Wv};
    __half* outs[3] = {qh, kh, vh};

    #pragma unroll
    for (int mtx = 0; mtx < 3; ++mtx) {
        const float* W = Ws[mtx];
        #pragma unroll
        for (int n0 = 0; n0 < 64; n0 += 16) {
            int col = n0 + m16;
            f32x4 acc = {0.f, 0.f, 0.f, 0.f};
            #pragma unroll
            for (int kk = 0; kk < 2; ++kk) {
                bf16x8 bfrag;
                #pragma unroll
                for (int j = 0; j < 8; ++j)
                    bfrag[j] = (short)f2bf(W[(kk * 32 + quad * 8 + j) * DIM + col]);
                acc = __builtin_amdgcn_mfma_f32_16x16x32_bf16(afrag[kk], bfrag, acc, 0, 0, 0);
            }
            if (mtx == 0) {
                #pragma unroll
                for (int r = 0; r < 4; ++r) acc[r] *= 0.25f;  // fold 1/sqrt(HEAD_DIM)
            }
            #pragma unroll
            for (int r = 0; r < 4; ++r) {
                int gnode = blockIdx.x * 64 + w * 16 + quad * 4 + r;
                if (gnode < NN) outs[mtx][(size_t)gnode * DIM + col] = __float2half(acc[r]);
            }
        }
    }
}

// e_proj = edge_attr @ We, streaming MFMA GEMM. block = 64 edges (NE%64==0,
// no guards). attr read coalesced+nontemporal (read-once 205MB), out fp16.
__global__ __launch_bounds__(256) void eproj_mfma_kernel(
    const float* __restrict__ edge_attr, const float* __restrict__ We,
    __half* __restrict__ ep)
{
    int tid = threadIdx.x;
    int w = tid >> 6;
    int lane = tid & 63;
    int m16 = lane & 15;
    int quad = lane >> 4;
    int row = blockIdx.x * 64 + w * 16 + m16;  // edge index

    bf16x8 afrag[2];
    #pragma unroll
    for (int kk = 0; kk < 2; ++kk) {
        const fvec4* ar = (const fvec4*)(edge_attr + (size_t)row * DIM + kk * 32 + quad * 8);
        fvec4 a0 = __builtin_nontemporal_load(ar);
        fvec4 a1 = __builtin_nontemporal_load(ar + 1);
        afrag[kk][0] = (short)f2bf(a0.x); afrag[kk][1] = (short)f2bf(a0.y);
        afrag[kk][2] = (short)f2bf(a0.z); afrag[kk][3] = (short)f2bf(a0.w);
        afrag[kk][4] = (short)f2bf(a1.x); afrag[kk][5] = (short)f2bf(a1.y);
        afrag[kk][6] = (short)f2bf(a1.z); afrag[kk][7] = (short)f2bf(a1.w);
    }

    #pragma unroll
    for (int n0 = 0; n0 < 64; n0 += 16) {
        int col = n0 + m16;
        f32x4 acc = {0.f, 0.f, 0.f, 0.f};
        #pragma unroll
        for (int kk = 0; kk < 2; ++kk) {
            bf16x8 bfrag;
            #pragma unroll
            for (int j = 0; j < 8; ++j)
                bfrag[j] = (short)f2bf(We[(kk * 32 + quad * 8 + j) * DIM + col]);
            acc = __builtin_amdgcn_mfma_f32_16x16x32_bf16(afrag[kk], bfrag, acc, 0, 0, 0);
        }
        #pragma unroll
        for (int r = 0; r < 4; ++r) {
            int grow = blockIdx.x * 64 + w * 16 + quad * 4 + r;
            ep[(size_t)grow * DIM + col] = __float2half(acc[r]);
        }
    }
}

__global__ void init_kernel(int* __restrict__ deg, int* __restrict__ hist) {
    int i = blockIdx.x * 256 + threadIdx.x;
    if (i < NN) deg[i] = 0;
    if (i < 64) hist[i] = 0;
}

__global__ void deg_kernel(const int* __restrict__ ei, int* __restrict__ deg) {
    int e = blockIdx.x * 256 + threadIdx.x;
    if (e >= NE) return;
    atomicAdd(&deg[ei[NE + e]], 1);
}

__global__ void hist_kernel(const int* __restrict__ deg, int* __restrict__ hist) {
    int n = blockIdx.x * 256 + threadIdx.x;
    if (n >= NN) return;
    int d = deg[n]; if (d > 63) d = 63;
    atomicAdd(&hist[d], 1);
}

__global__ void binscan_kernel(const int* __restrict__ hist, int* __restrict__ bincur) {
    if (threadIdx.x == 0) {
        int acc = 0;
        for (int d = 0; d < 64; ++d) { bincur[d] = acc; acc += hist[d]; }
    }
}

// Degree-sorted permutation: perm[p] = node, rank[node] = p. Grouped-by-degree
// is all we need (any order within a bin is fine).
__global__ void permscatter_kernel(const int* __restrict__ deg, int* __restrict__ bincur,
                                   int* __restrict__ perm, int* __restrict__ rank) {
    int n = blockIdx.x * 256 + threadIdx.x;
    if (n >= NN) return;
    int d = deg[n]; if (d > 63) d = 63;
    int p = atomicAdd(&bincur[d], 1);
    perm[p] = n;
    rank[n] = p;
}

// Scans below operate on PERMUTED degree order -> row_ptr is in permuted order.
__global__ void blocksum_kernel(const int* __restrict__ deg, const int* __restrict__ perm,
                                int* __restrict__ bsum) {
    int t = threadIdx.x, b = blockIdx.x;
    int idx = b * 256 + t;
    int v = (idx < NN) ? deg[perm[idx]] : 0;
    #pragma unroll
    for (int off = 32; off > 0; off >>= 1) v += __shfl_down(v, off);
    __shared__ int wsum[4];
    if ((t & 63) == 0) wsum[t >> 6] = v;
    __syncthreads();
    if (t == 0) bsum[b] = wsum[0] + wsum[1] + wsum[2] + wsum[3];
}

__global__ void bscan_kernel(const int* __restrict__ bsum, int* __restrict__ boff) {
    __shared__ int s[512];
    int t = threadIdx.x;
    int v = (t < NBLK) ? bsum[t] : 0;
    s[t] = v;
    __syncthreads();
    for (int off = 1; off < 512; off <<= 1) {
        int u = (t >= off) ? s[t - off] : 0;
        __syncthreads();
        s[t] += u;
        __syncthreads();
    }
    if (t < NBLK) boff[t] = s[t] - v;
}

__global__ void rowptr_kernel(const int* __restrict__ deg, const int* __restrict__ perm,
                              const int* __restrict__ boff,
                              int* __restrict__ row_ptr, int* __restrict__ cursor) {
    __shared__ int s[256];
    int t = threadIdx.x, b = blockIdx.x;
    int idx = b * 256 + t;
    int v = (idx < NN) ? deg[perm[idx]] : 0;
    s[t] = v;
    __syncthreads();
    for (int off = 1; off < 256; off <<= 1) {
        int u = (t >= off) ? s[t - off] : 0;
        __syncthreads();
        s[t] += u;
        __syncthreads();
    }
    if (idx < NN) {
        int ex = boff[b] + s[t] - v;
        row_ptr[idx] = ex;
        cursor[idx] = ex;
    }
    if (idx == 0) row_ptr[NN] = NE;
}

__global__ void scatter_kernel(const int* __restrict__ ei,
                               const int* __restrict__ rank,
                               int* __restrict__ cursor,
                               int* __restrict__ csr_src,
                               int* __restrict__ csr_e,
                               int* __restrict__ csr_dst) {
    int e = blockIdx.x * 256 + threadIdx.x;
    if (e >= NE) return;
    int src = ei[e], dst = ei[NE + e];
    int pos = atomicAdd(&cursor[rank[dst]], 1);
    csr_src[pos] = src;
    csr_e[pos] = e;
    csr_dst[pos] = dst;
}

// CSR-order logits, one thread per slot, all 4 heads:
// logit_h = q[dst]·(k[src] + e_proj[e]) per head. Per slot only 3 random
// 128B rows (q cached across same-dst runs). Writes raw-exp recs directly.
__global__ __launch_bounds__(256) void logits_csr3_kernel(
    const __half* __restrict__ qh,
    const __half* __restrict__ kh,
    const __half* __restrict__ ep,
    const int* __restrict__ csr_src,
    const int* __restrict__ csr_e,
    const int* __restrict__ csr_dst,
    uint4* __restrict__ recs) {
    int j = blockIdx.x * 256 + threadIdx.x;
    if (j >= NE) return;
    int src = csr_src[j], dst = csr_dst[j], e = csr_e[j];
    const uvec4* qq = (const uvec4*)qh + (size_t)dst * 8;
    const uvec4* kk = (const uvec4*)kh + (size_t)src * 8;
    const uvec4* ee = (const uvec4*)ep + (size_t)e * 8;
    float lg[4];
    #pragma unroll
    for (int h = 0; h < 4; ++h) {
        uvec4 q0 = qq[2 * h], q1 = qq[2 * h + 1];
        uvec4 k0 = kk[2 * h], k1 = kk[2 * h + 1];
        uvec4 e0 = __builtin_nontemporal_load(ee + 2 * h);
        uvec4 e1 = __builtin_nontemporal_load(ee + 2 * h + 1);
        lg[h] = dot8s(q0, k0, e0) + dot8s(q1, k1, e1);
    }
    uint4 rec;
    rec.x = (unsigned int)src;
    rec.y = f2h2(__expf(lg[0]), __expf(lg[1]));  // logits bounded ~8; exp < 3000, fp16-safe
    rec.z = f2h2(__expf(lg[2]), __expf(lg[3]));
    rec.w = 0u;
    recs[j] = rec;
}

// Per permuted-row pass: sum raw exps -> rinv, rescale recs in place.
// Degree-sorted rows => wave-uniform loops.
__global__ void recs_fused_kernel(uint4* __restrict__ recs,
                                  const int* __restrict__ row_ptr) {
    int n = blockIdx.x * 256 + threadIdx.x;
    if (n >= NN) return;
    int beg = row_ptr[n], end = row_ptr[n + 1];
    float s0 = 1e-16f, s1 = 1e-16f, s2 = 1e-16f, s3 = 1e-16f;
    for (int j = beg; j < end; ++j) {
        uint4 ap = recs[j];
        float2 p01 = h2f(ap.y), p23 = h2f(ap.z);
        s0 += p01.x; s1 += p01.y; s2 += p23.x; s3 += p23.y;
    }
    float r0 = 0.9f / s0, r1 = 0.9f / s1, r2 = 0.9f / s2, r3 = 0.9f / s3;
    for (int j = beg; j < end; ++j) {
        uint4 ap = recs[j];
        float2 p01 = h2f(ap.y), p23 = h2f(ap.z);
        ap.y = f2h2(p01.x * r0, p01.y * r1);
        ap.z = f2h2(p23.x * r2, p23.y * r3);
        recs[j] = ap;
    }
}

// Propagation: 8 lanes/node, 8 dims/lane. Rows in degree-sorted (permuted)
// order -> uniform waves; node identity via perm for v/zout addressing.
// z arrays stay in ORIGINAL node order (gathers use stored src ids).
__global__ __launch_bounds__(256) void prop_rec_kernel(
    const __half* __restrict__ zin,
    const __half* __restrict__ vh,
    const uint4* __restrict__ recs,
    const int* __restrict__ row_ptr,
    const int* __restrict__ perm,
    __half* __restrict__ zout) {
    int gid = blockIdx.x * 256 + threadIdx.x;
    int grp = gid >> 3;
    if (grp >= NN) return;
    int node = perm[grp];
    int l = gid & 7;
    int head = l >> 1;
    const uint4* z4 = (const uint4*)zin;
    float m[8];
    #pragma unroll
    for (int i = 0; i < 8; ++i) m[i] = 0.f;
    int beg = row_ptr[grp], end = row_ptr[grp + 1];
    int j = beg;
    for (; j + 8 <= end; j += 8) {
        uint4 r[8], zz[8];
        #pragma unroll
        for (int t = 0; t < 8; ++t) r[t] = recs[j + t];
        #pragma unroll
        for (int t = 0; t < 8; ++t) zz[t] = z4[(size_t)r[t].x * 8 + l];
        #pragma unroll
        for (int t = 0; t < 8; ++t) { float a = rec_att(r[t], head); ACC8(a, zz[t]); }
    }
    for (; j + 4 <= end; j += 4) {
        uint4 r0 = recs[j], r1 = recs[j + 1], r2 = recs[j + 2], r3 = recs[j + 3];
        uint4 z0 = z4[(size_t)r0.x * 8 + l];
        uint4 z1 = z4[(size_t)r1.x * 8 + l];
        uint4 z2 = z4[(size_t)r2.x * 8 + l];
        uint4 z3 = z4[(size_t)r3.x * 8 + l];
        float a0 = rec_att(r0, head), a1 = rec_att(r1, head);
        float a2 = rec_att(r2, head), a3 = rec_att(r3, head);
        ACC8(a0, z0); ACC8(a1, z1); ACC8(a2, z2); ACC8(a3, z3);
    }
    for (; j < end; ++j) {
        uint4 r = recs[j];
        uint4 zl = z4[(size_t)r.x * 8 + l];
        float a = rec_att(r, head);
        ACC8(a, zl);
    }
    uint4 vv = ((const uint4*)vh)[(size_t)node * 8 + l];
    float2 v0 = h2f(vv.x), v1 = h2f(vv.y), v2 = h2f(vv.z), v3 = h2f(vv.w);
    uint4 o;
    o.x = f2h2(ALPHA * v0.x + m[0], ALPHA * v0.y + m[1]);
    o.y = f2h2(ALPHA * v1.x + m[2], ALPHA * v1.y + m[3]);
    o.z = f2h2(ALPHA * v2.x + m[4], ALPHA * v2.y + m[5]);
    o.w = f2h2(ALPHA * v3.x + m[6], ALPHA * v3.y + m[7]);
    ((uint4*)zout)[(size_t)node * 8 + l] = o;
}

// Final iteration fused with epilogue: out = x + relu(z_new), fp32 out.
__global__ __launch_bounds__(256) void prop_out_rec_kernel(
    const __half* __restrict__ zin,
    const __half* __restrict__ vh,
    const uint4* __restrict__ recs,
    const int* __restrict__ row_ptr,
    const int* __restrict__ perm,
    const float* __restrict__ x,
    float* __restrict__ out) {
    int gid = blockIdx.x * 256 + threadIdx.x;
    int grp = gid >> 3;
    if (grp >= NN) return;
    int node = perm[grp];
    int l = gid & 7;
    int head = l >> 1;
    const uint4* z4 = (const uint4*)zin;
    float m[8];
    #pragma unroll
    for (int i = 0; i < 8; ++i) m[i] = 0.f;
    int beg = row_ptr[grp], end = row_ptr[grp + 1];
    int j = beg;
    for (; j + 8 <= end; j += 8) {
        uint4 r[8], zz[8];
        #pragma unroll
        for (int t = 0; t < 8; ++t) r[t] = recs[j + t];
        #pragma unroll
        for (int t = 0; t < 8; ++t) zz[t] = z4[(size_t)r[t].x * 8 + l];
        #pragma unroll
        for (int t = 0; t < 8; ++t) { float a = rec_att(r[t], head); ACC8(a, zz[t]); }
    }
    for (; j + 4 <= end; j += 4) {
        uint4 r0 = recs[j], r1 = recs[j + 1], r2 = recs[j + 2], r3 = recs[j + 3];
        uint4 z0 = z4[(size_t)r0.x * 8 + l];
        uint4 z1 = z4[(size_t)r1.x * 8 + l];
        uint4 z2 = z4[(size_t)r2.x * 8 + l];
        uint4 z3 = z4[(size_t)r3.x * 8 + l];
        float a0 = rec_att(r0, head), a1 = rec_att(r1, head);
        float a2 = rec_att(r2, head), a3 = rec_att(r3, head);
        ACC8(a0, z0); ACC8(a1, z1); ACC8(a2, z2); ACC8(a3, z3);
    }
    for (; j < end; ++j) {
        uint4 r = recs[j];
        uint4 zl = z4[(size_t)r.x * 8 + l];
        float a = rec_att(r, head);
        ACC8(a, zl);
    }
    uint4 vv = ((const uint4*)vh)[(size_t)node * 8 + l];
    float2 v0 = h2f(vv.x), v1 = h2f(vv.y), v2 = h2f(vv.z), v3 = h2f(vv.w);
    float zf[8] = { ALPHA * v0.x + m[0], ALPHA * v0.y + m[1],
                    ALPHA * v1.x + m[2], ALPHA * v1.y + m[3],
                    ALPHA * v2.x + m[4], ALPHA * v2.y + m[5],
                    ALPHA * v3.x + m[6], ALPHA * v3.y + m[7] };
    const float4* x4 = (const float4*)x + (size_t)node * 16 + l * 2;
    float4 xa = x4[0], xb = x4[1];
    float4 oa, ob;
    oa.x = xa.x + fmaxf(zf[0], 0.f); oa.y = xa.y + fmaxf(zf[1], 0.f);
    oa.z = xa.z + fmaxf(zf[2], 0.f); oa.w = xa.w + fmaxf(zf[3], 0.f);
    ob.x = xb.x + fmaxf(zf[4], 0.f); ob.y = xb.y + fmaxf(zf[5], 0.f);
    ob.z = xb.z + fmaxf(zf[6], 0.f); ob.w = xb.w + fmaxf(zf[7], 0.f);
    float4* o4 = (float4*)out + (size_t)node * 16 + l * 2;
    o4[0] = oa; o4[1] = ob;
}

extern "C" void kernel_launch(void* const* d_in, const int* in_sizes, int n_in,
                              void* d_out, int out_size, void* d_ws, size_t ws_size,
                              hipStream_t stream) {
    const float* x         = (const float*)d_in[0];
    const int*   ei        = (const int*)d_in[1];   // [2, NE]: row0=src, row1=dst
    const float* edge_attr = (const float*)d_in[2];
    const float* Wq        = (const float*)d_in[3];
    const float* Wk        = (const float*)d_in[4];
    const float* Wv        = (const float*)d_in[5];
    const float* We        = (const float*)d_in[6];
    float* out = (float*)d_out;

    // ws layout (~166 MB). z double-buffers ALIAS e_proj (e_proj dead after
    // logits; z first written after recs). All segments 16B-aligned.
    __half* qh = (__half*)d_ws;                          // NN*64
    __half* kh = qh + (size_t)NN * DIM;                  // NN*64
    __half* vh = kh + (size_t)NN * DIM;                  // NN*64
    __half* ep = vh + (size_t)NN * DIM;                  // NE*64 fp16 (102.4 MB)
    __half* zha = ep;                                    // alias (NN*64)
    __half* zhb = zha + (size_t)NN * DIM;                // alias (NN*64)
    uint4* recs  = (uint4*)(ep + (size_t)NE * DIM);      // NE (16B each)
    int* deg     = (int*)(recs + (size_t)NE);            // NN
    int* perm    = deg + NN;                             // NN
    int* rank    = perm + NN;                            // NN
    int* hist    = rank + NN;                            // 64
    int* bincur  = hist + 64;                            // 64
    int* bsum    = bincur + 64;                          // NBLK
    int* boff    = bsum + NBLK;                          // NBLK
    int* row_ptr = boff + NBLK;                          // NN+1
    int* cursor  = row_ptr + NN + 1;                     // NN
    int* csr_src = cursor + NN;                          // NE
    int* csr_e   = csr_src + NE;                         // NE
    int* csr_dst = csr_e + NE;                           // NE

    hipLaunchKernelGGL(qkv_mfma_kernel, dim3((NN + 63) / 64), dim3(256), 0, stream,
                       x, Wq, Wk, Wv, qh, kh, vh);
    hipLaunchKernelGGL(eproj_mfma_kernel, dim3(NE / 64), dim3(256), 0, stream,
                       edge_attr, We, ep);
    hipLaunchKernelGGL(init_kernel, dim3((NN + 255) / 256), dim3(256), 0, stream,
                       deg, hist);
    hipLaunchKernelGGL(deg_kernel, dim3((NE + 255) / 256), dim3(256), 0, stream,
                       ei, deg);
    hipLaunchKernelGGL(hist_kernel, dim3(NBLK), dim3(256), 0, stream,
                       deg, hist);
    hipLaunchKernelGGL(binscan_kernel, dim3(1), dim3(64), 0, stream,
                       hist, bincur);
    hipLaunchKernelGGL(permscatter_kernel, dim3(NBLK), dim3(256), 0, stream,
                       deg, bincur, perm, rank);
    hipLaunchKernelGGL(blocksum_kernel, dim3(NBLK), dim3(256), 0, stream,
                       deg, perm, bsum);
    hipLaunchKernelGGL(bscan_kernel, dim3(1), dim3(512), 0, stream,
                       bsum, boff);
    hipLaunchKernelGGL(rowptr_kernel, dim3(NBLK), dim3(256), 0, stream,
                       deg, perm, boff, row_ptr, cursor);
    hipLaunchKernelGGL(scatter_kernel, dim3((NE + 255) / 256), dim3(256), 0, stream,
                       ei, rank, cursor, csr_src, csr_e, csr_dst);
    hipLaunchKernelGGL(logits_csr3_kernel, dim3((NE + 255) / 256), dim3(256), 0, stream,
                       qh, kh, ep, csr_src, csr_e, csr_dst, recs);
    hipLaunchKernelGGL(recs_fused_kernel, dim3((NN + 255) / 256), dim3(256), 0, stream,
                       recs, row_ptr);

    const __half* zin = vh;
    __half* zout = zha;
    for (int it = 0; it < K_ITERS - 1; ++it) {
        hipLaunchKernelGGL(prop_rec_kernel, dim3((NN * 8 + 255) / 256), dim3(256), 0, stream,
                           zin, vh, recs, row_ptr, perm, zout);
        zin = zout;
        zout = (zout == zha) ? zhb : zha;
    }
    hipLaunchKernelGGL(prop_out_rec_kernel, dim3((NN * 8 + 255) / 256), dim3(256), 0, stream,
                       zin, vh, recs, row_ptr, perm, x, out);
}